// Round 6
// baseline (2002.627 us; speedup 1.0000x reference)
//
#include <hip/hip_runtime.h>
#include <stdint.h>

typedef _Float16 half_t;
typedef _Float16 half2_t __attribute__((ext_vector_type(2)));

#define NN   256
#define TT   1280
#define INF  128
#define HH   256
#define MM   128
#define OUTF 64
#define HM   384

#define THREADS 512

// ---- LDS layout (bytes) ----
#define LDS_PRED    0          // half[256*256] = 131072
#define LDS_PROC    131072     // int[1280]     = 5120
#define LDS_PARENT  136192     // int[1280]     = 5120
#define LDS_FMSG    141312     // half[128]     = 256
#define LDS_V2      141568     // half[2][384]  = 1536  ([ns 256 | msg 128] x2 buffers)
#define SMEM_BYTES  143104

// ---- d_ws layout (bytes) ----
#define WS_PRED0    0          // half[256*256]       = 131072
#define WS_WSH      131072     // half[256*384]       = 196608
#define WS_WMH      327680     // half[128*384]       =  98304
#define WS_MSGS     425984     // half[256*1280*128]  = 83886080

__device__ __forceinline__ float dot2f(half2_t a, half2_t b, float c) {
#if __has_builtin(__builtin_amdgcn_fdot2)
  return __builtin_amdgcn_fdot2(a, b, c, false);
#else
  return c + (float)a[0] * (float)b[0] + (float)a[1] * (float)b[1];
#endif
}

template <int CTRL>
__device__ __forceinline__ float dpp_add(float x) {
  int xi = __float_as_int(x);
  int yi = __builtin_amdgcn_update_dpp(xi, xi, CTRL, 0xf, 0xf, false);
  return x + __int_as_float(yi);
}
// full sum across each 16-lane DPP row: xor1, xor2, half_mirror, mirror
__device__ __forceinline__ float row16_reduce(float x) {
  x = dpp_add<0xB1>(x);   // quad_perm [1,0,3,2]
  x = dpp_add<0x4E>(x);   // quad_perm [2,3,0,1]
  x = dpp_add<0x141>(x);  // row_half_mirror
  x = dpp_add<0x140>(x);  // row_mirror
  return x;
}

// ---------------- weight prep: fp32 -> fp16 copies of Ws, Wm ----------------
__global__ __launch_bounds__(256)
void prep_kernel(const float* __restrict__ Ws, const float* __restrict__ Wm,
                 half_t* __restrict__ WsH, half_t* __restrict__ WmH)
{
  const int i = blockIdx.x * 256 + threadIdx.x;     // grid covers 147456
  if (i < HH * HM) WsH[i] = (half_t)Ws[i];
  else             WmH[i - HH * HM] = (half_t)Wm[i - HH * HM];
}

// ---------------- encoder: pred0 = x @ We.T + be  (fp16 out) ----------------
__global__ __launch_bounds__(256)
void enc_kernel(const float* __restrict__ x, const float* __restrict__ We,
                const float* __restrict__ be, half_t* __restrict__ pred0)
{
  __shared__ float xs[INF];
  const int n = blockIdx.x;
  const int hh = threadIdx.x;
  if (hh < INF) xs[hh] = x[n * INF + hh];
  __syncthreads();
  const float* w = We + hh * INF;
  float acc = be[hh];
#pragma unroll 16
  for (int k = 0; k < INF; ++k) acc += w[k] * xs[k];
  pred0[n * HH + hh] = (half_t)acc;
}

// ---------------- main persistent kernel: one run per workgroup ----------------
// Lane mapping: wave = tid>>6, dpp-row = (lane>>4), colgroup c = lane&15.
// rowgroup rg = wave*4 + dpp-row  (32 groups).
// Phase 1: lane computes rows rg*8..rg*8+7 over cols [c*24, c*24+24).
// Phase 2: lane computes rows rg*4..rg*4+3 over the same col slice.
// Partials reduced across the 16-lane col groups via DPP adds (no DS ops).
__global__ __launch_bounds__(THREADS, 2)
void sim_kernel(const half_t* __restrict__ WsH, const float* __restrict__ bs,
                const half_t* __restrict__ WmH, const float* __restrict__ bm,
                const float* __restrict__ Wd, const float* __restrict__ bd,
                const float* __restrict__ fmsg,
                const int* __restrict__ proc, const int* __restrict__ parent,
                const half_t* __restrict__ pred0,
                half_t* __restrict__ msgs,
                float* __restrict__ out)
{
  extern __shared__ char smem[];
  half_t* lds_pred        = (half_t*)(smem + LDS_PRED);
  int* lds_proc           = (int*)(smem + LDS_PROC);
  int* lds_par            = (int*)(smem + LDS_PARENT);
  half_t* lds_fmsg        = (half_t*)(smem + LDS_FMSG);
  char* v2base            = smem + LDS_V2;   // half[2][384]: [ns(256)|msg(128)]

  const int tid  = threadIdx.x;
  const int run  = blockIdx.x;
  const int wave = tid >> 6;
  const int lane = tid & 63;
  const int c    = lane & 15;               // colgroup (16 per DPP row)
  const int rg   = wave * 4 + (lane >> 4);  // rowgroup 0..31
  const int obyte = c * 48;                 // byte offset of this lane's col slice

  // ---- weights -> pinned registers (packed half2 as int) ----
  int w1i[96];   // phase 1: 8 rows x 12 half2
  {
    const char* wb = (const char*)WsH + (size_t)(rg * 8) * (HM * 2) + obyte;
#pragma unroll
    for (int r = 0; r < 8; ++r)
#pragma unroll
      for (int jj = 0; jj < 3; ++jj) {
        int4 v = *(const int4*)(wb + r * (HM * 2) + jj * 16);
        w1i[r * 12 + jj * 4 + 0] = v.x;
        w1i[r * 12 + jj * 4 + 1] = v.y;
        w1i[r * 12 + jj * 4 + 2] = v.z;
        w1i[r * 12 + jj * 4 + 3] = v.w;
      }
  }
  int w2i[48];   // phase 2: 4 rows x 12 half2
  {
    const char* wb = (const char*)WmH + (size_t)(rg * 4) * (HM * 2) + obyte;
#pragma unroll
    for (int r = 0; r < 4; ++r)
#pragma unroll
      for (int jj = 0; jj < 3; ++jj) {
        int4 v = *(const int4*)(wb + r * (HM * 2) + jj * 16);
        w2i[r * 12 + jj * 4 + 0] = v.x;
        w2i[r * 12 + jj * 4 + 1] = v.y;
        w2i[r * 12 + jj * 4 + 2] = v.z;
        w2i[r * 12 + jj * 4 + 3] = v.w;
      }
  }
  // pin: values become opaque -> allocator cannot rematerialize the loads
#pragma unroll
  for (int j = 0; j < 96; ++j) asm volatile("" : "+v"(w1i[j]));
#pragma unroll
  for (int j = 0; j < 48; ++j) asm volatile("" : "+v"(w2i[j]));

  const float bs1 = (c < 8) ? bs[rg * 8 + c] : 0.f;
  const float bm1 = (c < 4) ? bm[rg * 4 + c] : 0.f;

  // ---- LDS init: pred0 copy, schedule, first_message ----
  {
    const uint4* s = (const uint4*)pred0;
    uint4* d = (uint4*)lds_pred;
#pragma unroll
    for (int i = 0; i < (NN * HH * 2 / 16) / THREADS; ++i)   // 16 iters
      d[tid + i * THREADS] = s[tid + i * THREADS];
  }
  {
    const int* procR = proc + run * TT;
    const int* parR  = parent + run * TT;
    for (int i = tid; i < TT; i += THREADS) {
      lds_proc[i] = procR[i];
      lds_par[i]  = parR[i];
    }
  }
  if (tid < MM) lds_fmsg[tid] = (half_t)fmsg[tid];
  __syncthreads();

  half_t* msgs_run = msgs + (size_t)run * TT * MM;

  // ---- stage msg(0) into buffer 0 ----
  {
    const int p0 = lds_par[0];
    if (tid < 16) {
      uint4 v;
      if (p0 < 0) v = *(const uint4*)((const char*)lds_fmsg + tid * 16);
      else        v = *(const uint4*)((const char*)(msgs_run + (size_t)p0 * MM) + tid * 16);
      *(uint4*)(v2base + 512 + tid * 16) = v;
    }
  }
  __syncthreads();

  uint4 pfB = make_uint4(0, 0, 0, 0);

  // ---- main loop: 2 barriers per step ----
  int b = 0;
  for (int t = 0; t < TT; ++t, b ^= 1) {
    const int node  = lds_proc[t];
    const int vld   = (t == 0) | (lds_par[t] >= 0);   // exact valid reconstruction
    const int parn1 = (t + 1 < TT) ? lds_par[t + 1] : -1;
    const int parn2 = (t + 2 < TT) ? lds_par[t + 2] : -1;

    const bool useA = (parn1 >= 0) && (parn1 == t - 1);
    uint4 pfA;
    if (tid < 16 && useA)
      pfA = *(const uint4*)((const char*)(msgs_run + (size_t)parn1 * MM) + tid * 16);

    // ---- phase 1: ns = relu(Ws @ [pred[node] | msg] + bs) ----
    const char* predrow = (const char*)(lds_pred + node * HH);
    const char* msgb    = v2base + b * 768 + 512;
    int av[12];
    {
#pragma unroll
      for (int j = 0; j < 3; ++j) {
        const int o = obyte + j * 16;                      // chunk start, 16B aligned
        const char* p = (o < 512) ? (predrow + o) : (msgb + (o - 512));
        int4 A = *(const int4*)p;
        av[j * 4 + 0] = A.x; av[j * 4 + 1] = A.y;
        av[j * 4 + 2] = A.z; av[j * 4 + 3] = A.w;
      }
    }
    float acc0 = 0.f, acc1 = 0.f, acc2_ = 0.f, acc3 = 0.f;
    float acc4 = 0.f, acc5 = 0.f, acc6 = 0.f, acc7 = 0.f;
#pragma unroll
    for (int k = 0; k < 12; ++k) {
      const half2_t a = __builtin_bit_cast(half2_t, av[k]);
      acc0 = dot2f(a, __builtin_bit_cast(half2_t, w1i[0 * 12 + k]), acc0);
      acc1 = dot2f(a, __builtin_bit_cast(half2_t, w1i[1 * 12 + k]), acc1);
      acc2_ = dot2f(a, __builtin_bit_cast(half2_t, w1i[2 * 12 + k]), acc2_);
      acc3 = dot2f(a, __builtin_bit_cast(half2_t, w1i[3 * 12 + k]), acc3);
      acc4 = dot2f(a, __builtin_bit_cast(half2_t, w1i[4 * 12 + k]), acc4);
      acc5 = dot2f(a, __builtin_bit_cast(half2_t, w1i[5 * 12 + k]), acc5);
      acc6 = dot2f(a, __builtin_bit_cast(half2_t, w1i[6 * 12 + k]), acc6);
      acc7 = dot2f(a, __builtin_bit_cast(half2_t, w1i[7 * 12 + k]), acc7);
    }
    float nsv = 0.f;
    {
      float s;
      s = row16_reduce(acc0); if (c == 0) nsv = s;
      s = row16_reduce(acc1); if (c == 1) nsv = s;
      s = row16_reduce(acc2_); if (c == 2) nsv = s;
      s = row16_reduce(acc3); if (c == 3) nsv = s;
      s = row16_reduce(acc4); if (c == 4) nsv = s;
      s = row16_reduce(acc5); if (c == 5) nsv = s;
      s = row16_reduce(acc6); if (c == 6) nsv = s;
      s = row16_reduce(acc7); if (c == 7) nsv = s;
    }
    nsv = fmaxf(nsv + bs1, 0.f);
    const half_t nsh = (half_t)nsv;
    if (c < 8) ((half_t*)(v2base + b * 768))[rg * 8 + c] = nsh;   // ns -> v2[b]

    // ---- stage msg(t+1) into buffer b^1 ----
    if (t + 1 < TT && tid < 16) {
      char* dst = v2base + (b ^ 1) * 768 + 512 + tid * 16;
      if (parn1 < 0)
        *(uint4*)dst = *(const uint4*)((const char*)lds_fmsg + tid * 16);
      else if (parn1 != t)                 // parn1==t handled by phase-2 fixup
        *(uint4*)dst = useA ? pfA : pfB;
    }
    // early prefetch for msg(t+2) (rows <= t-1 are all safely stored)
    if (tid < 16 && parn2 >= 0 && parn2 < t)
      pfB = *(const uint4*)((const char*)(msgs_run + (size_t)parn2 * MM) + tid * 16);

    __syncthreads();   // ns + staged msg visible

    // ---- phase 2: nm = Wm @ [ns | msg] + bm ----
    const char* v2b = v2base + b * 768;
    int bv[12];
    {
#pragma unroll
      for (int j = 0; j < 3; ++j) {
        int4 B = *(const int4*)(v2b + obyte + j * 16);
        bv[j * 4 + 0] = B.x; bv[j * 4 + 1] = B.y;
        bv[j * 4 + 2] = B.z; bv[j * 4 + 3] = B.w;
      }
    }
    float m0 = 0.f, m1 = 0.f, m2 = 0.f, m3 = 0.f;
#pragma unroll
    for (int k = 0; k < 12; ++k) {
      const half2_t a = __builtin_bit_cast(half2_t, bv[k]);
      m0 = dot2f(a, __builtin_bit_cast(half2_t, w2i[0 * 12 + k]), m0);
      m1 = dot2f(a, __builtin_bit_cast(half2_t, w2i[1 * 12 + k]), m1);
      m2 = dot2f(a, __builtin_bit_cast(half2_t, w2i[2 * 12 + k]), m2);
      m3 = dot2f(a, __builtin_bit_cast(half2_t, w2i[3 * 12 + k]), m3);
    }
    float nmv = 0.f;
    {
      float s;
      s = row16_reduce(m0); if (c == 0) nmv = s;
      s = row16_reduce(m1); if (c == 1) nmv = s;
      s = row16_reduce(m2); if (c == 2) nmv = s;
      s = row16_reduce(m3); if (c == 3) nmv = s;
    }
    if (c < 4) {
      nmv += bm1;
      const half_t nmh = vld ? (half_t)nmv : (half_t)0.f;
      const int row2 = rg * 4 + c;
      if (vld) msgs_run[(size_t)t * MM + row2] = nmh;
      if (parn1 == t)                       // next step consumes this message
        ((half_t*)(v2base + (b ^ 1) * 768 + 512))[row2] = nmh;
    }
    if (c < 8 && vld)
      lds_pred[node * HH + rg * 8 + c] = nsh;   // safe: phase 2 reads only v2
    __syncthreads();   // phase-2 reads done; buffer b free; msg(t+1) visible
  }

  // ---- epilogue: out[run] = log_softmax(Wd @ pred[run] + bd) ----
  if (tid < OUTF) {
    const float* wd = Wd + tid * HH;
    float acc = bd[tid];
#pragma unroll 8
    for (int k = 0; k < HH; ++k) acc += wd[k] * (float)lds_pred[run * HH + k];
    float m = acc;
#pragma unroll
    for (int off = 32; off >= 1; off >>= 1) m = fmaxf(m, __shfl_xor(m, off));
    const float e = __expf(acc - m);
    float s = e;
#pragma unroll
    for (int off = 32; off >= 1; off >>= 1) s += __shfl_xor(s, off);
    out[run * OUTF + tid] = acc - m - logf(s);
  }
}

extern "C" void kernel_launch(void* const* d_in, const int* in_sizes, int n_in,
                              void* d_out, int out_size, void* d_ws, size_t ws_size,
                              hipStream_t stream) {
  (void)in_sizes; (void)n_in; (void)out_size; (void)ws_size;
  const float* x    = (const float*)d_in[0];
  const float* fm   = (const float*)d_in[1];
  const float* We   = (const float*)d_in[2];
  const float* be   = (const float*)d_in[3];
  const float* Ws   = (const float*)d_in[4];
  const float* bs   = (const float*)d_in[5];
  const float* Wm   = (const float*)d_in[6];
  const float* bm   = (const float*)d_in[7];
  const float* Wd   = (const float*)d_in[8];
  const float* bd   = (const float*)d_in[9];
  const int* proc   = (const int*)d_in[10];
  const int* parent = (const int*)d_in[11];
  // d_in[12] (valid) unused: reconstructed as (t==0)||parent>=0 (exact).
  float* out = (float*)d_out;

  half_t* pred0 = (half_t*)((char*)d_ws + WS_PRED0);
  half_t* WsH   = (half_t*)((char*)d_ws + WS_WSH);
  half_t* WmH   = (half_t*)((char*)d_ws + WS_WMH);
  half_t* msgs  = (half_t*)((char*)d_ws + WS_MSGS);

  (void)hipFuncSetAttribute((const void*)sim_kernel,
                            hipFuncAttributeMaxDynamicSharedMemorySize, SMEM_BYTES);

  prep_kernel<<<dim3((HH * HM + MM * HM) / 256), dim3(256), 0, stream>>>(Ws, Wm, WsH, WmH);
  enc_kernel<<<dim3(NN), dim3(256), 0, stream>>>(x, We, be, pred0);
  sim_kernel<<<dim3(NN), dim3(THREADS), SMEM_BYTES, stream>>>(
      WsH, bs, WmH, bm, Wd, bd, fm, proc, parent, pred0, msgs, out);
}